// Round 10
// baseline (298.101 us; speedup 1.0000x reference)
//
#include <hip/hip_runtime.h>
#include <math.h>

#define LL 1026          // sequence length S*S+2
#define EDim 512
#define MM 2052          // B0*LL
#define NC 16            // scan chunks (last chunk = 66 steps, others 64)
#define LC 64

struct Params {
  const float* cw[4];
  const float* cb[4];
  const float* xpw[4];
  const float* dtw[4];
  const float* dtb[4];
  const float* Al[4];
  const float* Dp[4];
};

// branch position l -> original position
__device__ __forceinline__ int sigma_map(int branch, int l) {
  if (branch & 1) l = LL - 1 - l;          // reverse
  if (branch & 2) {                        // S x S transpose of inner block
    if (l > 0 && l < LL - 1) {
      int p = l - 1;
      l = 1 + ((p & 31) << 5) + (p >> 5);
    }
  }
  return l;
}

__device__ __forceinline__ float silu_f(float v) {
  return v * __builtin_amdgcn_rcpf(1.f + __expf(-v));
}
__device__ __forceinline__ float softplus_f(float s) {
  return fmaxf(s, 0.f) + __logf(1.f + __expf(-fabsf(s)));
}

template<int CTRL>
__device__ __forceinline__ float dpp_mov0(float x) {
  int r = __builtin_amdgcn_update_dpp(0, __float_as_int(x), CTRL, 0xF, 0xF, false);
  return __int_as_float(r);
}

// 16-lane sum, result valid in lane 15 of each 16-lane group
__device__ __forceinline__ float red16(float r) {
  r += dpp_mov0<0xB1>(r);    // quad_perm xor1
  r += dpp_mov0<0x4E>(r);    // quad_perm xor2
  r += dpp_mov0<0x114>(r);   // row_shr:4
  r += dpp_mov0<0x118>(r);   // row_shr:8
  return r;
}

// ---------------------------------------------------------------------------
// k1: xz = x @ in_w^T ; split into xa and sz = silu(za)
// BM=64 BN=32 BK=32 -> grid (33,32)=1056 blocks (4/CU). acc 4x2/thread.
// ---------------------------------------------------------------------------
__global__ __launch_bounds__(256) void k1_gemm_in(
    const float* __restrict__ x, const float* __restrict__ w,
    float* __restrict__ xa, float* __restrict__ sz) {
  __shared__ float As[32][68];
  __shared__ float Bs[32][36];
  const int t = threadIdx.x;
  const int tx = t & 15, ty = t >> 4;
  const int m0 = blockIdx.x * 64, n0 = blockIdx.y * 32;
  float acc[4][2] = {};
  for (int k0 = 0; k0 < 256; k0 += 32) {
    #pragma unroll
    for (int p = 0; p < 2; ++p) {
      int f = t + p * 256;            // 0..511
      int row = f >> 3, cf = f & 7;   // 64 rows x 8 float4
      int gr = m0 + row; gr = gr < MM ? gr : MM - 1;
      float4 v = *(const float4*)(x + (size_t)gr * 256 + k0 + cf * 4);
      As[cf*4+0][row] = v.x; As[cf*4+1][row] = v.y;
      As[cf*4+2][row] = v.z; As[cf*4+3][row] = v.w;
    }
    {
      int row = t >> 3, cf = t & 7;   // 32 rows x 8 float4
      float4 u = *(const float4*)(w + (size_t)(n0 + row) * 256 + k0 + cf * 4);
      Bs[cf*4+0][row] = u.x; Bs[cf*4+1][row] = u.y;
      Bs[cf*4+2][row] = u.z; Bs[cf*4+3][row] = u.w;
    }
    __syncthreads();
    #pragma unroll
    for (int k = 0; k < 32; ++k) {
      float4 av = *(const float4*)&As[k][ty*4];
      float2 bv = *(const float2*)&Bs[k][tx*2];
      acc[0][0]=fmaf(av.x,bv.x,acc[0][0]); acc[0][1]=fmaf(av.x,bv.y,acc[0][1]);
      acc[1][0]=fmaf(av.y,bv.x,acc[1][0]); acc[1][1]=fmaf(av.y,bv.y,acc[1][1]);
      acc[2][0]=fmaf(av.z,bv.x,acc[2][0]); acc[2][1]=fmaf(av.z,bv.y,acc[2][1]);
      acc[3][0]=fmaf(av.w,bv.x,acc[3][0]); acc[3][1]=fmaf(av.w,bv.y,acc[3][1]);
    }
    __syncthreads();
  }
  #pragma unroll
  for (int i = 0; i < 4; ++i) {
    int gm = m0 + ty*4 + i;
    if (gm < MM) {
      #pragma unroll
      for (int j = 0; j < 2; ++j) {
        int gn = n0 + tx*2 + j;
        float v = acc[i][j];
        if (gn < 512) xa[(size_t)gm*512 + gn] = v;
        else          sz[(size_t)gm*512 + gn - 512] = silu_f(v);
      }
    }
  }
}

// ---------------------------------------------------------------------------
// k2a: conv(K=4, causal, depthwise)+silu -> xac. NO LDS, NO barriers.
// 8-row tiles -> grid (129,2,4)=1032 blocks (4/CU). br==0 zeroes acc.
// ---------------------------------------------------------------------------
__global__ __launch_bounds__(256) void k2a_conv(
    Params P, const float* __restrict__ xa, float* __restrict__ xac,
    float* __restrict__ acc_out) {
  const int t = threadIdx.x;
  const int l0 = blockIdx.x * 8;
  const int b  = blockIdx.y;
  const int br = blockIdx.z;
  const int e0 = 2 * t;

  if (br == 0 && l0 < LL) {
    int nrow = LL - l0; if (nrow > 8) nrow = 8;
    float* ab = acc_out + ((size_t)b * LL + l0) * 512;
    for (int idx = t; idx < nrow * 512; idx += 256) ab[idx] = 0.f;
  }

  const float* cw = P.cw[br];
  const float w00 = cw[e0*4+0], w01 = cw[e0*4+1], w02 = cw[e0*4+2], w03 = cw[e0*4+3];
  const float w10 = cw[(e0+1)*4+0], w11 = cw[(e0+1)*4+1], w12 = cw[(e0+1)*4+2], w13 = cw[(e0+1)*4+3];
  const float cb0 = P.cb[br][e0], cb1 = P.cb[br][e0+1];
  const float* xab = xa + (size_t)b * LL * 512;
  float* xob = xac + ((size_t)(br*2 + b) * LL) * 512;

  float h0x=0,h0y=0,h1x=0,h1y=0,h2x=0,h2y=0,h3x=0,h3y=0;
  #pragma unroll
  for (int i = -3; i < 8; ++i) {
    int l = l0 + i;
    float cx = 0.f, cy = 0.f;
    if (l >= 0 && l < LL) {
      int pos = sigma_map(br, l);
      float2 v = *(const float2*)(xab + (size_t)pos * 512 + e0);
      cx = v.x; cy = v.y;
    }
    h0x=h1x; h0y=h1y; h1x=h2x; h1y=h2y; h2x=h3x; h2y=h3y; h3x=cx; h3y=cy;
    if (i >= 0 && l < LL) {
      float o0 = fmaf(w00,h0x, fmaf(w01,h1x, fmaf(w02,h2x, fmaf(w03,h3x, cb0))));
      float o1 = fmaf(w10,h0y, fmaf(w11,h1y, fmaf(w12,h2y, fmaf(w13,h3y, cb1))));
      *(float2*)(xob + (size_t)l * 512 + e0) = make_float2(silu_f(o0), silu_f(o1));
    }
  }
}

// ---------------------------------------------------------------------------
// k2b: dBC = xc @ xpw^T ; delta = softplus(dBC[:,:16]@dtw^T + dtb); store B,C.
// Stages the 16-row xc tile from xac (coalesced float4), then projection with
// weights direct from global (16-lane-shared addresses, L2 resident).
// ---------------------------------------------------------------------------
__global__ __launch_bounds__(256) void k2b_proj(
    Params P, const float* __restrict__ xac,
    float* __restrict__ delta, float* __restrict__ bcg) {
  __shared__ float xcS[16][516];
  __shared__ float dBCs[16][49];
  const int t = threadIdx.x;
  const int l0 = blockIdx.x * 16;
  const int b  = blockIdx.y;
  const int br = blockIdx.z;
  const int e0 = 2 * t;
  const size_t obase = (size_t)(br*2 + b) * LL;

  // stage xc tile (zeros for out-of-range rows)
  #pragma unroll
  for (int p = 0; p < 8; ++p) {
    int idx = t + p*256;             // 0..2047
    int row = idx >> 7, c4 = idx & 127;
    int l = l0 + row;
    float4 v = make_float4(0.f,0.f,0.f,0.f);
    if (l < LL) v = *(const float4*)(xac + (obase + l)*512 + c4*4);
    *(float4*)&xcS[row][c4*4] = v;
  }
  __syncthreads();

  // projection: thread -> (row = t&15, r-cols r0, r0+16, r0+32), K=512
  const int rowi = t & 15;
  const int r0 = t >> 4;
  const float* xpw = P.xpw[br];
  const float4* xr4 = (const float4*)&xcS[rowi][0];
  const float4* wa = (const float4*)(xpw + (size_t)r0 * 512);
  const float4* wb = (const float4*)(xpw + (size_t)(r0 + 16) * 512);
  const float4* wc = (const float4*)(xpw + (size_t)(r0 + 32) * 512);
  float acc0 = 0.f, acc1 = 0.f, acc2 = 0.f;
  #pragma unroll 8
  for (int e4 = 0; e4 < 128; ++e4) {
    float4 xv = xr4[e4];
    float4 a = wa[e4], bb = wb[e4], c = wc[e4];
    acc0 = fmaf(xv.x,a.x, fmaf(xv.y,a.y, fmaf(xv.z,a.z, fmaf(xv.w,a.w, acc0))));
    acc1 = fmaf(xv.x,bb.x,fmaf(xv.y,bb.y,fmaf(xv.z,bb.z,fmaf(xv.w,bb.w,acc1))));
    acc2 = fmaf(xv.x,c.x, fmaf(xv.y,c.y, fmaf(xv.z,c.z, fmaf(xv.w,c.w, acc2))));
  }
  dBCs[rowi][r0]      = acc0;
  dBCs[rowi][r0 + 16] = acc1;
  dBCs[rowi][r0 + 32] = acc2;
  __syncthreads();

  // store B, C
  for (int idx = t; idx < 512; idx += 256) {
    int row = idx >> 5, c = idx & 31;
    int l = l0 + row;
    if (l < LL) bcg[(obase + l)*32 + c] = dBCs[row][16 + c];
  }

  // delta = softplus(dBC[:, :16] @ dtw^T + dtb)
  const float* dtw = P.dtw[br];
  float dw0[16], dw1[16];
  #pragma unroll
  for (int r = 0; r < 16; ++r) { dw0[r] = dtw[e0*16 + r]; dw1[r] = dtw[(e0+1)*16 + r]; }
  const float db0 = P.dtb[br][e0], db1 = P.dtb[br][e0+1];
  for (int row = 0; row < 16; ++row) {
    int l = l0 + row;
    if (l >= LL) break;
    float s0 = db0, s1 = db1;
    #pragma unroll
    for (int r = 0; r < 16; ++r) {
      float d = dBCs[row][r];
      s0 = fmaf(d, dw0[r], s0);
      s1 = fmaf(d, dw1[r], s1);
    }
    *(float2*)(delta + (obase + l)*512 + e0) = make_float2(softplus_f(s0), softplus_f(s1));
  }
}

// ---------------------------------------------------------------------------
// k3a: per-chunk scan summaries.  P_c = exp(A_en * sum delta), Q_c = local
// scan (h_in=0).  float4 staging, b128 LDS reads, 4-step register batches.
// ---------------------------------------------------------------------------
__global__ __launch_bounds__(256) void k3a_chunk(
    Params P, const float* __restrict__ xac, const float* __restrict__ delta,
    const float* __restrict__ bcg, float* __restrict__ Pc, float* __restrict__ Qc) {
  __shared__ float dT[16][36], xT[16][36], bT[16][36];
  const int t = threadIdx.x;
  const int eL = t >> 4, n = t & 15;
  const int e0 = blockIdx.x * 16;
  const int b = blockIdx.y;
  const int br = blockIdx.z / NC, c = blockIdx.z % NC;
  const size_t sbase = (size_t)(br*2 + b) * LL;
  const float* dl = delta + sbase * 512;
  const float* xc = xac + sbase * 512;
  const float* bc = bcg + sbase * 32;
  const float A_en = -__expf(P.Al[br][(e0 + eL)*16 + n]);
  const int l0 = c * LC;
  const int lend = (c == NC-1) ? LL : (l0 + LC);
  float h = 0.f, dsum = 0.f;

  for (int c0 = l0; c0 < lend; c0 += 32) {
    {
      const int idx = t & 127;
      const int s = idx >> 2, q = idx & 3;
      const int l = c0 + s;
      float4 v = make_float4(0.f,0.f,0.f,0.f);
      if (t < 128) {
        if (l < lend) v = *(const float4*)(dl + (size_t)l*512 + e0 + q*4);
        dT[q*4+0][s]=v.x; dT[q*4+1][s]=v.y; dT[q*4+2][s]=v.z; dT[q*4+3][s]=v.w;
        float4 u = make_float4(0.f,0.f,0.f,0.f);
        if (l < lend) u = *(const float4*)(bc + (size_t)l*32 + q*4);
        bT[q*4+0][s]=u.x; bT[q*4+1][s]=u.y; bT[q*4+2][s]=u.z; bT[q*4+3][s]=u.w;
      } else {
        if (l < lend) v = *(const float4*)(xc + (size_t)l*512 + e0 + q*4);
        xT[q*4+0][s]=v.x; xT[q*4+1][s]=v.y; xT[q*4+2][s]=v.z; xT[q*4+3][s]=v.w;
      }
    }
    __syncthreads();
    #pragma unroll
    for (int s4 = 0; s4 < 32; s4 += 4) {
      float4 dv = *(const float4*)&dT[eL][s4];
      float4 xv = *(const float4*)&xT[eL][s4];
      float4 bv = *(const float4*)&bT[n][s4];
      float g0 = __expf(dv.x*A_en), g1 = __expf(dv.y*A_en);
      float g2 = __expf(dv.z*A_en), g3 = __expf(dv.w*A_en);
      dsum += (dv.x+dv.y)+(dv.z+dv.w);
      h = fmaf(g0, h, dv.x*xv.x*bv.x);
      h = fmaf(g1, h, dv.y*xv.y*bv.y);
      h = fmaf(g2, h, dv.z*xv.z*bv.z);
      h = fmaf(g3, h, dv.w*xv.w*bv.w);
    }
    __syncthreads();
  }
  size_t oi = ((((size_t)(br*2 + b)*NC + c)*32 + blockIdx.x)*256 + t);
  Pc[oi] = __expf(dsum * A_en);
  Qc[oi] = h;
}

// ---------------------------------------------------------------------------
// k3b: chunk-parallel output scan; gated result atomically accumulated
// (x0.25) into acc.
// ---------------------------------------------------------------------------
__global__ __launch_bounds__(256) void k3b_scan(
    Params P, const float* __restrict__ xac, const float* __restrict__ delta,
    const float* __restrict__ bcg, const float* __restrict__ sz,
    const float* __restrict__ Pc, const float* __restrict__ Qc,
    float* __restrict__ acc_out) {
  __shared__ float dT[16][36], xT[16][36], bT[16][36], cT[16][36];
  __shared__ float yb[16][36];
  const int t = threadIdx.x;
  const int eL = t >> 4, n = t & 15;
  const int e0 = blockIdx.x * 16;
  const int b = blockIdx.y;
  const int br = blockIdx.z / NC, c = blockIdx.z % NC;
  const size_t sbase = (size_t)(br*2 + b) * LL;
  const float* dl = delta + sbase * 512;
  const float* xc = xac + sbase * 512;
  const float* bc = bcg + sbase * 32;
  const float A_en = -__expf(P.Al[br][(e0 + eL)*16 + n]);
  const float Dval = P.Dp[br][e0 + (t & 15)];
  const float* szb = sz + (size_t)b * LL * 512;
  float* ab = acc_out + (size_t)b * LL * 512;

  // h_in: h[c] = P[c-1]*h[c-1] + Q[c-1], h[0]=0
  float h = 0.f;
  for (int cc = 0; cc < c; ++cc) {
    size_t ii = ((((size_t)(br*2 + b)*NC + cc)*32 + blockIdx.x)*256 + t);
    h = fmaf(Pc[ii], h, Qc[ii]);
  }

  const int l0c = c * LC;
  const int lend = (c == NC-1) ? LL : (l0c + LC);
  for (int c0 = l0c; c0 < lend; c0 += 32) {
    {
      const int idx = t & 127;
      const int s = idx >> 2, q = idx & 3;
      const int l = c0 + s;
      float4 v = make_float4(0.f,0.f,0.f,0.f);
      if (t < 128) {
        if (l < lend) v = *(const float4*)(dl + (size_t)l*512 + e0 + q*4);
        dT[q*4+0][s]=v.x; dT[q*4+1][s]=v.y; dT[q*4+2][s]=v.z; dT[q*4+3][s]=v.w;
      } else {
        if (l < lend) v = *(const float4*)(xc + (size_t)l*512 + e0 + q*4);
        xT[q*4+0][s]=v.x; xT[q*4+1][s]=v.y; xT[q*4+2][s]=v.z; xT[q*4+3][s]=v.w;
      }
    }
    {
      const int s = t >> 3, q = t & 7;
      const int l = c0 + s;
      float4 u = make_float4(0.f,0.f,0.f,0.f);
      if (l < lend) u = *(const float4*)(bc + (size_t)l*32 + q*4);
      if (q < 4) {
        bT[q*4+0][s]=u.x; bT[q*4+1][s]=u.y; bT[q*4+2][s]=u.z; bT[q*4+3][s]=u.w;
      } else {
        int q4 = (q-4)*4;
        cT[q4+0][s]=u.x; cT[q4+1][s]=u.y; cT[q4+2][s]=u.z; cT[q4+3][s]=u.w;
      }
    }
    __syncthreads();

    #pragma unroll
    for (int s4 = 0; s4 < 32; s4 += 4) {
      float4 dv = *(const float4*)&dT[eL][s4];
      float4 xv = *(const float4*)&xT[eL][s4];
      float4 bv = *(const float4*)&bT[n][s4];
      float4 cv = *(const float4*)&cT[n][s4];
      float r0, r1, r2, r3;
      h = fmaf(__expf(dv.x*A_en), h, dv.x*xv.x*bv.x); r0 = red16(h*cv.x);
      h = fmaf(__expf(dv.y*A_en), h, dv.y*xv.y*bv.y); r1 = red16(h*cv.y);
      h = fmaf(__expf(dv.z*A_en), h, dv.z*xv.z*bv.z); r2 = red16(h*cv.z);
      h = fmaf(__expf(dv.w*A_en), h, dv.w*xv.w*bv.w); r3 = red16(h*cv.w);
      if (n == 15) *(float4*)&yb[eL][s4] = make_float4(r0, r1, r2, r3);
    }
    __syncthreads();

    #pragma unroll
    for (int p = 0; p < 2; ++p) {
      int idx = t + p*256;
      int s = idx >> 4, ee = idx & 15;
      int l = c0 + s;
      if (l < lend) {
        float yv = fmaf(Dval, xT[ee][s], yb[ee][s]);
        int pos = sigma_map(br, l);
        float szv = szb[(size_t)pos * 512 + e0 + ee];
        atomicAdd(ab + (size_t)pos * 512 + e0 + ee, 0.25f * yv * szv);
      }
    }
    __syncthreads();
  }
}

// ---------------------------------------------------------------------------
// k4: out = acc @ out_w^T.  M=2052 N=256 K=512.
// BM=16 BN=32 -> grid (129,8)=1032 blocks (4/CU), 7 KB LDS.
// ---------------------------------------------------------------------------
__global__ __launch_bounds__(256) void k4_gemm_out(
    const float* __restrict__ acc_in, const float* __restrict__ w,
    float* __restrict__ out) {
  __shared__ float As[32][20];
  __shared__ float Bs[32][36];
  const int t = threadIdx.x;
  const int tx = t & 15, ty = t >> 4;   // ty = output row 0..15
  const int m0 = blockIdx.x * 16, n0 = blockIdx.y * 32;
  float a0 = 0.f, a1 = 0.f;
  for (int k0 = 0; k0 < 512; k0 += 32) {
    #pragma unroll
    for (int p = 0; p < 2; ++p) {
      int idx = t + p*256;
      int row = idx >> 5, kk = idx & 31;
      int gm = m0 + row; gm = gm < MM ? gm : MM - 1;
      As[kk][row] = acc_in[(size_t)gm*512 + k0 + kk];
    }
    #pragma unroll
    for (int p = 0; p < 4; ++p) {
      int idx = t + p*256;
      int row = idx >> 5, kk = idx & 31;
      Bs[kk][row] = w[(size_t)(n0 + row)*512 + k0 + kk];
    }
    __syncthreads();
    #pragma unroll
    for (int k = 0; k < 32; ++k) {
      float av = As[k][ty];
      float2 bv = *(const float2*)&Bs[k][tx*2];
      a0 = fmaf(av, bv.x, a0);
      a1 = fmaf(av, bv.y, a1);
    }
    __syncthreads();
  }
  int gm = m0 + ty;
  if (gm < MM) {
    out[(size_t)gm*256 + n0 + tx*2 + 0] = a0;
    out[(size_t)gm*256 + n0 + tx*2 + 1] = a1;
  }
}

// ---------------------------------------------------------------------------
extern "C" void kernel_launch(void* const* d_in, const int* in_sizes, int n_in,
                              void* d_out, int out_size, void* d_ws, size_t ws_size,
                              hipStream_t stream) {
  const float* x    = (const float*)d_in[0];
  const float* in_w = (const float*)d_in[1];
  const float* out_w= (const float*)d_in[2];
  Params prm;
  for (int s = 0; s < 4; ++s) {
    prm.cw[s]  = (const float*)d_in[3 + s*7 + 0];
    prm.cb[s]  = (const float*)d_in[3 + s*7 + 1];
    prm.xpw[s] = (const float*)d_in[3 + s*7 + 2];
    prm.dtw[s] = (const float*)d_in[3 + s*7 + 3];
    prm.dtb[s] = (const float*)d_in[3 + s*7 + 4];
    prm.Al[s]  = (const float*)d_in[3 + s*7 + 5];
    prm.Dp[s]  = (const float*)d_in[3 + s*7 + 6];
  }
  float* ws = (float*)d_ws;
  const size_t SZ1 = (size_t)MM * 512;        // 1,050,624 floats
  float* xa   = ws;                            // [MM][512]
  float* szp  = ws + SZ1;                      // [MM][512]
  float* xac  = ws + 2*SZ1;                    // [4][MM][512] branch-ordered
  float* dlt  = ws + 6*SZ1;                    // [4][MM][512]
  float* bc   = ws + 10*SZ1;                   // [4][MM][32]
  float* acc  = ws + 10*SZ1 + (size_t)4*MM*32; // [MM][512]  summed gated output
  float* Pc   = acc + SZ1;                     // [8][NC][32][256]
  float* Qc   = Pc + (size_t)8*NC*32*256;      // same size

  k1_gemm_in<<<dim3(33, 32), 256, 0, stream>>>(x, in_w, xa, szp);
  k2a_conv  <<<dim3(129, 2, 4), 256, 0, stream>>>(prm, xa, xac, acc);
  k2b_proj  <<<dim3(65, 2, 4), 256, 0, stream>>>(prm, xac, dlt, bc);
  k3a_chunk <<<dim3(32, 2, 4*NC), 256, 0, stream>>>(prm, xac, dlt, bc, Pc, Qc);
  k3b_scan  <<<dim3(32, 2, 4*NC), 256, 0, stream>>>(prm, xac, dlt, bc, szp, Pc, Qc, acc);
  k4_gemm_out<<<dim3(129, 8), 256, 0, stream>>>(acc, out_w, (float*)d_out);
}

// Round 12
// 281.244 us; speedup vs baseline: 1.0599x; 1.0599x over previous
//
#include <hip/hip_runtime.h>
#include <math.h>

#define LL 1026          // sequence length S*S+2
#define EDim 512
#define MM 2052          // B0*LL
#define NC 16            // scan chunks (last chunk = 66 steps, others 64)
#define LC 64

struct Params {
  const float* cw[4];
  const float* cb[4];
  const float* xpw[4];
  const float* dtw[4];
  const float* dtb[4];
  const float* Al[4];
  const float* Dp[4];
};

// branch position l -> original position
__device__ __forceinline__ int sigma_map(int branch, int l) {
  if (branch & 1) l = LL - 1 - l;          // reverse
  if (branch & 2) {                        // S x S transpose of inner block
    if (l > 0 && l < LL - 1) {
      int p = l - 1;
      l = 1 + ((p & 31) << 5) + (p >> 5);
    }
  }
  return l;
}

__device__ __forceinline__ float silu_f(float v) {
  return v * __builtin_amdgcn_rcpf(1.f + __expf(-v));
}
__device__ __forceinline__ float softplus_f(float s) {
  return fmaxf(s, 0.f) + __logf(1.f + __expf(-fabsf(s)));
}

template<int CTRL>
__device__ __forceinline__ float dpp_mov0(float x) {
  int r = __builtin_amdgcn_update_dpp(0, __float_as_int(x), CTRL, 0xF, 0xF, false);
  return __int_as_float(r);
}

// 16-lane sum, result valid in lane 15 of each 16-lane group
__device__ __forceinline__ float red16(float r) {
  r += dpp_mov0<0xB1>(r);    // quad_perm xor1
  r += dpp_mov0<0x4E>(r);    // quad_perm xor2
  r += dpp_mov0<0x114>(r);   // row_shr:4
  r += dpp_mov0<0x118>(r);   // row_shr:8
  return r;
}

// ---------------------------------------------------------------------------
// k1: xz = x @ in_w^T ; split into xa and sz = silu(za)
// BM=64 BN=64 BK=32 grid (33,16) [round-8 best]. launch_bounds(256,2):
// grid is 2 blocks/CU -> release VGPRs for deep load pipelining.
// ---------------------------------------------------------------------------
__global__ __launch_bounds__(256, 2) void k1_gemm_in(
    const float* __restrict__ x, const float* __restrict__ w,
    float* __restrict__ xa, float* __restrict__ sz) {
  __shared__ float As[32][68];
  __shared__ float Bs[32][68];
  const int t = threadIdx.x;
  const int tx = t & 15, ty = t >> 4;
  const int m0 = blockIdx.x * 64, n0 = blockIdx.y * 64;
  float acc[4][4] = {};
  for (int k0 = 0; k0 < 256; k0 += 32) {
    #pragma unroll
    for (int p = 0; p < 2; ++p) {
      int f = t + p * 256;            // 0..511
      int row = f >> 3, cf = f & 7;   // 64 rows x 8 float4
      int gr = m0 + row; gr = gr < MM ? gr : MM - 1;
      float4 v = *(const float4*)(x + (size_t)gr * 256 + k0 + cf * 4);
      As[cf*4+0][row] = v.x; As[cf*4+1][row] = v.y;
      As[cf*4+2][row] = v.z; As[cf*4+3][row] = v.w;
      int gn = n0 + row;
      float4 u = *(const float4*)(w + (size_t)gn * 256 + k0 + cf * 4);
      Bs[cf*4+0][row] = u.x; Bs[cf*4+1][row] = u.y;
      Bs[cf*4+2][row] = u.z; Bs[cf*4+3][row] = u.w;
    }
    __syncthreads();
    #pragma unroll
    for (int k = 0; k < 32; ++k) {
      float4 av = *(const float4*)&As[k][ty*4];
      float4 bv = *(const float4*)&Bs[k][tx*4];
      float a0 = av.x, a1 = av.y, a2 = av.z, a3 = av.w;
      float b0 = bv.x, b1 = bv.y, b2 = bv.z, b3 = bv.w;
      acc[0][0]=fmaf(a0,b0,acc[0][0]); acc[0][1]=fmaf(a0,b1,acc[0][1]); acc[0][2]=fmaf(a0,b2,acc[0][2]); acc[0][3]=fmaf(a0,b3,acc[0][3]);
      acc[1][0]=fmaf(a1,b0,acc[1][0]); acc[1][1]=fmaf(a1,b1,acc[1][1]); acc[1][2]=fmaf(a1,b2,acc[1][2]); acc[1][3]=fmaf(a1,b3,acc[1][3]);
      acc[2][0]=fmaf(a2,b0,acc[2][0]); acc[2][1]=fmaf(a2,b1,acc[2][1]); acc[2][2]=fmaf(a2,b2,acc[2][2]); acc[2][3]=fmaf(a2,b3,acc[2][3]);
      acc[3][0]=fmaf(a3,b0,acc[3][0]); acc[3][1]=fmaf(a3,b1,acc[3][1]); acc[3][2]=fmaf(a3,b2,acc[3][2]); acc[3][3]=fmaf(a3,b3,acc[3][3]);
    }
    __syncthreads();
  }
  #pragma unroll
  for (int i = 0; i < 4; ++i) {
    int gm = m0 + ty*4 + i;
    if (gm < MM) {
      #pragma unroll
      for (int j = 0; j < 4; ++j) {
        int gn = n0 + tx*4 + j;
        float v = acc[i][j];
        if (gn < 512) xa[(size_t)gm*512 + gn] = v;
        else          sz[(size_t)gm*512 + gn - 512] = silu_f(v);
      }
    }
  }
}

// ---------------------------------------------------------------------------
// k2a: conv(K=4, causal, depthwise)+silu -> xac. NO LDS, NO barriers.
// 8-row tiles -> grid (129,2,4)=1032 blocks (4/CU). br==0 zeroes acc.
// ---------------------------------------------------------------------------
__global__ __launch_bounds__(256, 4) void k2a_conv(
    Params P, const float* __restrict__ xa, float* __restrict__ xac,
    float* __restrict__ acc_out) {
  const int t = threadIdx.x;
  const int l0 = blockIdx.x * 8;
  const int b  = blockIdx.y;
  const int br = blockIdx.z;
  const int e0 = 2 * t;

  if (br == 0 && l0 < LL) {
    int nrow = LL - l0; if (nrow > 8) nrow = 8;
    float* ab = acc_out + ((size_t)b * LL + l0) * 512;
    for (int idx = t; idx < nrow * 512; idx += 256) ab[idx] = 0.f;
  }

  const float* cw = P.cw[br];
  const float w00 = cw[e0*4+0], w01 = cw[e0*4+1], w02 = cw[e0*4+2], w03 = cw[e0*4+3];
  const float w10 = cw[(e0+1)*4+0], w11 = cw[(e0+1)*4+1], w12 = cw[(e0+1)*4+2], w13 = cw[(e0+1)*4+3];
  const float cb0 = P.cb[br][e0], cb1 = P.cb[br][e0+1];
  const float* xab = xa + (size_t)b * LL * 512;
  float* xob = xac + ((size_t)(br*2 + b) * LL) * 512;

  float h0x=0,h0y=0,h1x=0,h1y=0,h2x=0,h2y=0,h3x=0,h3y=0;
  #pragma unroll
  for (int i = -3; i < 8; ++i) {
    int l = l0 + i;
    float cx = 0.f, cy = 0.f;
    if (l >= 0 && l < LL) {
      int pos = sigma_map(br, l);
      float2 v = *(const float2*)(xab + (size_t)pos * 512 + e0);
      cx = v.x; cy = v.y;
    }
    h0x=h1x; h0y=h1y; h1x=h2x; h1y=h2y; h2x=h3x; h2y=h3y; h3x=cx; h3y=cy;
    if (i >= 0 && l < LL) {
      float o0 = fmaf(w00,h0x, fmaf(w01,h1x, fmaf(w02,h2x, fmaf(w03,h3x, cb0))));
      float o1 = fmaf(w10,h0y, fmaf(w11,h1y, fmaf(w12,h2y, fmaf(w13,h3y, cb1))));
      *(float2*)(xob + (size_t)l * 512 + e0) = make_float2(silu_f(o0), silu_f(o1));
    }
  }
}

// ---------------------------------------------------------------------------
// k2b: dBC = xc @ xpw^T ; delta = softplus(dBC[:,:16]@dtw^T + dtb); store B,C.
// launch_bounds(256,2): grid is 2 blocks/CU; the 384 L2-latency weight loads
// per thread need a deep prefetch window -> release the VGPR budget.
// ---------------------------------------------------------------------------
__global__ __launch_bounds__(256, 2) void k2b_proj(
    Params P, const float* __restrict__ xac,
    float* __restrict__ delta, float* __restrict__ bcg) {
  __shared__ float xcS[16][516];
  __shared__ float dBCs[16][49];
  const int t = threadIdx.x;
  const int l0 = blockIdx.x * 16;
  const int b  = blockIdx.y;
  const int br = blockIdx.z;
  const int e0 = 2 * t;
  const size_t obase = (size_t)(br*2 + b) * LL;

  // stage xc tile (zeros for out-of-range rows)
  #pragma unroll
  for (int p = 0; p < 8; ++p) {
    int idx = t + p*256;             // 0..2047
    int row = idx >> 7, c4 = idx & 127;
    int l = l0 + row;
    float4 v = make_float4(0.f,0.f,0.f,0.f);
    if (l < LL) v = *(const float4*)(xac + (obase + l)*512 + c4*4);
    *(float4*)&xcS[row][c4*4] = v;
  }
  __syncthreads();

  // projection: thread -> (row = t&15, r-cols r0, r0+16, r0+32), K=512
  const int rowi = t & 15;
  const int r0 = t >> 4;
  const float* xpw = P.xpw[br];
  const float4* xr4 = (const float4*)&xcS[rowi][0];
  const float4* wa = (const float4*)(xpw + (size_t)r0 * 512);
  const float4* wb = (const float4*)(xpw + (size_t)(r0 + 16) * 512);
  const float4* wc = (const float4*)(xpw + (size_t)(r0 + 32) * 512);
  float acc0 = 0.f, acc1 = 0.f, acc2 = 0.f;
  #pragma unroll 8
  for (int e4 = 0; e4 < 128; ++e4) {
    float4 xv = xr4[e4];
    float4 a = wa[e4], bb = wb[e4], c = wc[e4];
    acc0 = fmaf(xv.x,a.x, fmaf(xv.y,a.y, fmaf(xv.z,a.z, fmaf(xv.w,a.w, acc0))));
    acc1 = fmaf(xv.x,bb.x,fmaf(xv.y,bb.y,fmaf(xv.z,bb.z,fmaf(xv.w,bb.w,acc1))));
    acc2 = fmaf(xv.x,c.x, fmaf(xv.y,c.y, fmaf(xv.z,c.z, fmaf(xv.w,c.w, acc2))));
  }
  dBCs[rowi][r0]      = acc0;
  dBCs[rowi][r0 + 16] = acc1;
  dBCs[rowi][r0 + 32] = acc2;
  __syncthreads();

  // store B, C
  for (int idx = t; idx < 512; idx += 256) {
    int row = idx >> 5, c = idx & 31;
    int l = l0 + row;
    if (l < LL) bcg[(obase + l)*32 + c] = dBCs[row][16 + c];
  }

  // delta = softplus(dBC[:, :16] @ dtw^T + dtb)
  const float* dtw = P.dtw[br];
  float dw0[16], dw1[16];
  #pragma unroll
  for (int r = 0; r < 16; ++r) { dw0[r] = dtw[e0*16 + r]; dw1[r] = dtw[(e0+1)*16 + r]; }
  const float db0 = P.dtb[br][e0], db1 = P.dtb[br][e0+1];
  for (int row = 0; row < 16; ++row) {
    int l = l0 + row;
    if (l >= LL) break;
    float s0 = db0, s1 = db1;
    #pragma unroll
    for (int r = 0; r < 16; ++r) {
      float d = dBCs[row][r];
      s0 = fmaf(d, dw0[r], s0);
      s1 = fmaf(d, dw1[r], s1);
    }
    *(float2*)(delta + (obase + l)*512 + e0) = make_float2(softplus_f(s0), softplus_f(s1));
  }
}

// ---------------------------------------------------------------------------
// k3a: per-chunk scan summaries.  P_c = exp(A_en * sum delta), Q_c = local
// scan (h_in=0).  grid 4096 = 4 blocks/CU -> launch_bounds(256,4).
// ---------------------------------------------------------------------------
__global__ __launch_bounds__(256, 4) void k3a_chunk(
    Params P, const float* __restrict__ xac, const float* __restrict__ delta,
    const float* __restrict__ bcg, float* __restrict__ Pc, float* __restrict__ Qc) {
  __shared__ float dT[16][36], xT[16][36], bT[16][36];
  const int t = threadIdx.x;
  const int eL = t >> 4, n = t & 15;
  const int e0 = blockIdx.x * 16;
  const int b = blockIdx.y;
  const int br = blockIdx.z / NC, c = blockIdx.z % NC;
  const size_t sbase = (size_t)(br*2 + b) * LL;
  const float* dl = delta + sbase * 512;
  const float* xc = xac + sbase * 512;
  const float* bc = bcg + sbase * 32;
  const float A_en = -__expf(P.Al[br][(e0 + eL)*16 + n]);
  const int l0 = c * LC;
  const int lend = (c == NC-1) ? LL : (l0 + LC);
  float h = 0.f, dsum = 0.f;

  for (int c0 = l0; c0 < lend; c0 += 32) {
    {
      const int idx = t & 127;
      const int s = idx >> 2, q = idx & 3;
      const int l = c0 + s;
      float4 v = make_float4(0.f,0.f,0.f,0.f);
      if (t < 128) {
        if (l < lend) v = *(const float4*)(dl + (size_t)l*512 + e0 + q*4);
        dT[q*4+0][s]=v.x; dT[q*4+1][s]=v.y; dT[q*4+2][s]=v.z; dT[q*4+3][s]=v.w;
        float4 u = make_float4(0.f,0.f,0.f,0.f);
        if (l < lend) u = *(const float4*)(bc + (size_t)l*32 + q*4);
        bT[q*4+0][s]=u.x; bT[q*4+1][s]=u.y; bT[q*4+2][s]=u.z; bT[q*4+3][s]=u.w;
      } else {
        if (l < lend) v = *(const float4*)(xc + (size_t)l*512 + e0 + q*4);
        xT[q*4+0][s]=v.x; xT[q*4+1][s]=v.y; xT[q*4+2][s]=v.z; xT[q*4+3][s]=v.w;
      }
    }
    __syncthreads();
    #pragma unroll
    for (int s4 = 0; s4 < 32; s4 += 4) {
      float4 dv = *(const float4*)&dT[eL][s4];
      float4 xv = *(const float4*)&xT[eL][s4];
      float4 bv = *(const float4*)&bT[n][s4];
      float g0 = __expf(dv.x*A_en), g1 = __expf(dv.y*A_en);
      float g2 = __expf(dv.z*A_en), g3 = __expf(dv.w*A_en);
      dsum += (dv.x+dv.y)+(dv.z+dv.w);
      h = fmaf(g0, h, dv.x*xv.x*bv.x);
      h = fmaf(g1, h, dv.y*xv.y*bv.y);
      h = fmaf(g2, h, dv.z*xv.z*bv.z);
      h = fmaf(g3, h, dv.w*xv.w*bv.w);
    }
    __syncthreads();
  }
  size_t oi = ((((size_t)(br*2 + b)*NC + c)*32 + blockIdx.x)*256 + t);
  Pc[oi] = __expf(dsum * A_en);
  Qc[oi] = h;
}

// ---------------------------------------------------------------------------
// k3b: chunk-parallel output scan; gated result atomically accumulated
// (x0.25) into acc.  launch_bounds(256,4).
// ---------------------------------------------------------------------------
__global__ __launch_bounds__(256, 4) void k3b_scan(
    Params P, const float* __restrict__ xac, const float* __restrict__ delta,
    const float* __restrict__ bcg, const float* __restrict__ sz,
    const float* __restrict__ Pc, const float* __restrict__ Qc,
    float* __restrict__ acc_out) {
  __shared__ float dT[16][36], xT[16][36], bT[16][36], cT[16][36];
  __shared__ float yb[16][36];
  const int t = threadIdx.x;
  const int eL = t >> 4, n = t & 15;
  const int e0 = blockIdx.x * 16;
  const int b = blockIdx.y;
  const int br = blockIdx.z / NC, c = blockIdx.z % NC;
  const size_t sbase = (size_t)(br*2 + b) * LL;
  const float* dl = delta + sbase * 512;
  const float* xc = xac + sbase * 512;
  const float* bc = bcg + sbase * 32;
  const float A_en = -__expf(P.Al[br][(e0 + eL)*16 + n]);
  const float Dval = P.Dp[br][e0 + (t & 15)];
  const float* szb = sz + (size_t)b * LL * 512;
  float* ab = acc_out + (size_t)b * LL * 512;

  // h_in: h[c] = P[c-1]*h[c-1] + Q[c-1], h[0]=0
  float h = 0.f;
  for (int cc = 0; cc < c; ++cc) {
    size_t ii = ((((size_t)(br*2 + b)*NC + cc)*32 + blockIdx.x)*256 + t);
    h = fmaf(Pc[ii], h, Qc[ii]);
  }

  const int l0c = c * LC;
  const int lend = (c == NC-1) ? LL : (l0c + LC);
  for (int c0 = l0c; c0 < lend; c0 += 32) {
    {
      const int idx = t & 127;
      const int s = idx >> 2, q = idx & 3;
      const int l = c0 + s;
      float4 v = make_float4(0.f,0.f,0.f,0.f);
      if (t < 128) {
        if (l < lend) v = *(const float4*)(dl + (size_t)l*512 + e0 + q*4);
        dT[q*4+0][s]=v.x; dT[q*4+1][s]=v.y; dT[q*4+2][s]=v.z; dT[q*4+3][s]=v.w;
      } else {
        if (l < lend) v = *(const float4*)(xc + (size_t)l*512 + e0 + q*4);
        xT[q*4+0][s]=v.x; xT[q*4+1][s]=v.y; xT[q*4+2][s]=v.z; xT[q*4+3][s]=v.w;
      }
    }
    {
      const int s = t >> 3, q = t & 7;
      const int l = c0 + s;
      float4 u = make_float4(0.f,0.f,0.f,0.f);
      if (l < lend) u = *(const float4*)(bc + (size_t)l*32 + q*4);
      if (q < 4) {
        bT[q*4+0][s]=u.x; bT[q*4+1][s]=u.y; bT[q*4+2][s]=u.z; bT[q*4+3][s]=u.w;
      } else {
        int q4 = (q-4)*4;
        cT[q4+0][s]=u.x; cT[q4+1][s]=u.y; cT[q4+2][s]=u.z; cT[q4+3][s]=u.w;
      }
    }
    __syncthreads();

    #pragma unroll
    for (int s4 = 0; s4 < 32; s4 += 4) {
      float4 dv = *(const float4*)&dT[eL][s4];
      float4 xv = *(const float4*)&xT[eL][s4];
      float4 bv = *(const float4*)&bT[n][s4];
      float4 cv = *(const float4*)&cT[n][s4];
      float r0, r1, r2, r3;
      h = fmaf(__expf(dv.x*A_en), h, dv.x*xv.x*bv.x); r0 = red16(h*cv.x);
      h = fmaf(__expf(dv.y*A_en), h, dv.y*xv.y*bv.y); r1 = red16(h*cv.y);
      h = fmaf(__expf(dv.z*A_en), h, dv.z*xv.z*bv.z); r2 = red16(h*cv.z);
      h = fmaf(__expf(dv.w*A_en), h, dv.w*xv.w*bv.w); r3 = red16(h*cv.w);
      if (n == 15) *(float4*)&yb[eL][s4] = make_float4(r0, r1, r2, r3);
    }
    __syncthreads();

    #pragma unroll
    for (int p = 0; p < 2; ++p) {
      int idx = t + p*256;
      int s = idx >> 4, ee = idx & 15;
      int l = c0 + s;
      if (l < lend) {
        float yv = fmaf(Dval, xT[ee][s], yb[ee][s]);
        int pos = sigma_map(br, l);
        float szv = szb[(size_t)pos * 512 + e0 + ee];
        atomicAdd(ab + (size_t)pos * 512 + e0 + ee, 0.25f * yv * szv);
      }
    }
    __syncthreads();
  }
}

// ---------------------------------------------------------------------------
// k4: out = acc @ out_w^T.  M=2052 N=256 K=512.  BM=32 BN=32 grid (65,8)
// [round-8 best].  launch_bounds(256,2).
// ---------------------------------------------------------------------------
__global__ __launch_bounds__(256, 2) void k4_gemm_out(
    const float* __restrict__ acc_in, const float* __restrict__ w,
    float* __restrict__ out) {
  __shared__ float As[32][38];
  __shared__ float Bs[32][38];
  const int t = threadIdx.x;
  const int tx = t & 15, ty = t >> 4;
  const int m0 = blockIdx.x * 32, n0 = blockIdx.y * 32;
  float acc[2][2] = {};
  for (int k0 = 0; k0 < 512; k0 += 32) {
    #pragma unroll
    for (int p = 0; p < 4; ++p) {
      int idx = t + p*256;
      int row = idx >> 5, kk = idx & 31;
      int gm = m0 + row; gm = gm < MM ? gm : MM - 1;
      As[kk][row] = acc_in[(size_t)gm*512 + k0 + kk];
    }
    #pragma unroll
    for (int p = 0; p < 4; ++p) {
      int idx = t + p*256;
      int row = idx >> 5, kk = idx & 31;
      Bs[kk][row] = w[(size_t)(n0 + row)*512 + k0 + kk];
    }
    __syncthreads();
    #pragma unroll
    for (int k = 0; k < 32; ++k) {
      float2 av = *(const float2*)&As[k][ty*2];
      float2 bv = *(const float2*)&Bs[k][tx*2];
      acc[0][0]=fmaf(av.x,bv.x,acc[0][0]); acc[0][1]=fmaf(av.x,bv.y,acc[0][1]);
      acc[1][0]=fmaf(av.y,bv.x,acc[1][0]); acc[1][1]=fmaf(av.y,bv.y,acc[1][1]);
    }
    __syncthreads();
  }
  #pragma unroll
  for (int i = 0; i < 2; ++i) {
    int gm = m0 + ty*2 + i;
    if (gm < MM) {
      #pragma unroll
      for (int j = 0; j < 2; ++j)
        out[(size_t)gm*256 + n0 + tx*2 + j] = acc[i][j];
    }
  }
}

// ---------------------------------------------------------------------------
extern "C" void kernel_launch(void* const* d_in, const int* in_sizes, int n_in,
                              void* d_out, int out_size, void* d_ws, size_t ws_size,
                              hipStream_t stream) {
  const float* x    = (const float*)d_in[0];
  const float* in_w = (const float*)d_in[1];
  const float* out_w= (const float*)d_in[2];
  Params prm;
  for (int s = 0; s < 4; ++s) {
    prm.cw[s]  = (const float*)d_in[3 + s*7 + 0];
    prm.cb[s]  = (const float*)d_in[3 + s*7 + 1];
    prm.xpw[s] = (const float*)d_in[3 + s*7 + 2];
    prm.dtw[s] = (const float*)d_in[3 + s*7 + 3];
    prm.dtb[s] = (const float*)d_in[3 + s*7 + 4];
    prm.Al[s]  = (const float*)d_in[3 + s*7 + 5];
    prm.Dp[s]  = (const float*)d_in[3 + s*7 + 6];
  }
  float* ws = (float*)d_ws;
  const size_t SZ1 = (size_t)MM * 512;        // 1,050,624 floats
  float* xa   = ws;                            // [MM][512]
  float* szp  = ws + SZ1;                      // [MM][512]
  float* xac  = ws + 2*SZ1;                    // [4][MM][512] branch-ordered
  float* dlt  = ws + 6*SZ1;                    // [4][MM][512]
  float* bc   = ws + 10*SZ1;                   // [4][MM][32]
  float* acc  = ws + 10*SZ1 + (size_t)4*MM*32; // [MM][512]  summed gated output
  float* Pc   = acc + SZ1;                     // [8][NC][32][256]
  float* Qc   = Pc + (size_t)8*NC*32*256;      // same size

  k1_gemm_in<<<dim3(33, 16), 256, 0, stream>>>(x, in_w, xa, szp);
  k2a_conv  <<<dim3(129, 2, 4), 256, 0, stream>>>(prm, xa, xac, acc);
  k2b_proj  <<<dim3(65, 2, 4), 256, 0, stream>>>(prm, xac, dlt, bc);
  k3a_chunk <<<dim3(32, 2, 4*NC), 256, 0, stream>>>(prm, xac, dlt, bc, Pc, Qc);
  k3b_scan  <<<dim3(32, 2, 4*NC), 256, 0, stream>>>(prm, xac, dlt, bc, szp, Pc, Qc, acc);
  k4_gemm_out<<<dim3(65, 8), 256, 0, stream>>>(acc, out_w, (float*)d_out);
}

// Round 13
// 275.059 us; speedup vs baseline: 1.0838x; 1.0225x over previous
//
#include <hip/hip_runtime.h>
#include <math.h>

#define LL 1026          // sequence length S*S+2
#define EDim 512
#define MM 2052          // B0*LL
#define NC 16            // scan chunks (last chunk = 66 steps, others 64)
#define LC 64

struct Params {
  const float* cw[4];
  const float* cb[4];
  const float* xpw[4];
  const float* dtw[4];
  const float* dtb[4];
  const float* Al[4];
  const float* Dp[4];
};

// branch position l -> original position
__device__ __forceinline__ int sigma_map(int branch, int l) {
  if (branch & 1) l = LL - 1 - l;          // reverse
  if (branch & 2) {                        // S x S transpose of inner block
    if (l > 0 && l < LL - 1) {
      int p = l - 1;
      l = 1 + ((p & 31) << 5) + (p >> 5);
    }
  }
  return l;
}

__device__ __forceinline__ float silu_f(float v) {
  return v * __builtin_amdgcn_rcpf(1.f + __expf(-v));
}
__device__ __forceinline__ float softplus_f(float s) {
  return fmaxf(s, 0.f) + __logf(1.f + __expf(-fabsf(s)));
}

template<int CTRL>
__device__ __forceinline__ float dpp_mov0(float x) {
  int r = __builtin_amdgcn_update_dpp(0, __float_as_int(x), CTRL, 0xF, 0xF, false);
  return __int_as_float(r);
}

// 16-lane sum, result valid in lane 15 of each 16-lane group
__device__ __forceinline__ float red16(float r) {
  r += dpp_mov0<0xB1>(r);    // quad_perm xor1
  r += dpp_mov0<0x4E>(r);    // quad_perm xor2
  r += dpp_mov0<0x114>(r);   // row_shr:4
  r += dpp_mov0<0x118>(r);   // row_shr:8
  return r;
}

// ---------------------------------------------------------------------------
// k1: xz = x @ in_w^T ; split into xa and sz = silu(za)
// BM=64 BN=64 BK=32 grid (33,16).
// ---------------------------------------------------------------------------
__global__ __launch_bounds__(256, 2) void k1_gemm_in(
    const float* __restrict__ x, const float* __restrict__ w,
    float* __restrict__ xa, float* __restrict__ sz) {
  __shared__ float As[32][68];
  __shared__ float Bs[32][68];
  const int t = threadIdx.x;
  const int tx = t & 15, ty = t >> 4;
  const int m0 = blockIdx.x * 64, n0 = blockIdx.y * 64;
  float acc[4][4] = {};
  for (int k0 = 0; k0 < 256; k0 += 32) {
    #pragma unroll
    for (int p = 0; p < 2; ++p) {
      int f = t + p * 256;            // 0..511
      int row = f >> 3, cf = f & 7;   // 64 rows x 8 float4
      int gr = m0 + row; gr = gr < MM ? gr : MM - 1;
      float4 v = *(const float4*)(x + (size_t)gr * 256 + k0 + cf * 4);
      As[cf*4+0][row] = v.x; As[cf*4+1][row] = v.y;
      As[cf*4+2][row] = v.z; As[cf*4+3][row] = v.w;
      int gn = n0 + row;
      float4 u = *(const float4*)(w + (size_t)gn * 256 + k0 + cf * 4);
      Bs[cf*4+0][row] = u.x; Bs[cf*4+1][row] = u.y;
      Bs[cf*4+2][row] = u.z; Bs[cf*4+3][row] = u.w;
    }
    __syncthreads();
    #pragma unroll
    for (int k = 0; k < 32; ++k) {
      float4 av = *(const float4*)&As[k][ty*4];
      float4 bv = *(const float4*)&Bs[k][tx*4];
      float a0 = av.x, a1 = av.y, a2 = av.z, a3 = av.w;
      float b0 = bv.x, b1 = bv.y, b2 = bv.z, b3 = bv.w;
      acc[0][0]=fmaf(a0,b0,acc[0][0]); acc[0][1]=fmaf(a0,b1,acc[0][1]); acc[0][2]=fmaf(a0,b2,acc[0][2]); acc[0][3]=fmaf(a0,b3,acc[0][3]);
      acc[1][0]=fmaf(a1,b0,acc[1][0]); acc[1][1]=fmaf(a1,b1,acc[1][1]); acc[1][2]=fmaf(a1,b2,acc[1][2]); acc[1][3]=fmaf(a1,b3,acc[1][3]);
      acc[2][0]=fmaf(a2,b0,acc[2][0]); acc[2][1]=fmaf(a2,b1,acc[2][1]); acc[2][2]=fmaf(a2,b2,acc[2][2]); acc[2][3]=fmaf(a2,b3,acc[2][3]);
      acc[3][0]=fmaf(a3,b0,acc[3][0]); acc[3][1]=fmaf(a3,b1,acc[3][1]); acc[3][2]=fmaf(a3,b2,acc[3][2]); acc[3][3]=fmaf(a3,b3,acc[3][3]);
    }
    __syncthreads();
  }
  #pragma unroll
  for (int i = 0; i < 4; ++i) {
    int gm = m0 + ty*4 + i;
    if (gm < MM) {
      #pragma unroll
      for (int j = 0; j < 4; ++j) {
        int gn = n0 + tx*4 + j;
        float v = acc[i][j];
        if (gn < 512) xa[(size_t)gm*512 + gn] = v;
        else          sz[(size_t)gm*512 + gn - 512] = silu_f(v);
      }
    }
  }
}

// ---------------------------------------------------------------------------
// k2a: conv(K=4, causal, depthwise)+silu -> xac. NO LDS, NO barriers.
// ---------------------------------------------------------------------------
__global__ __launch_bounds__(256, 4) void k2a_conv(
    Params P, const float* __restrict__ xa, float* __restrict__ xac,
    float* __restrict__ acc_out) {
  const int t = threadIdx.x;
  const int l0 = blockIdx.x * 8;
  const int b  = blockIdx.y;
  const int br = blockIdx.z;
  const int e0 = 2 * t;

  if (br == 0 && l0 < LL) {
    int nrow = LL - l0; if (nrow > 8) nrow = 8;
    float* ab = acc_out + ((size_t)b * LL + l0) * 512;
    for (int idx = t; idx < nrow * 512; idx += 256) ab[idx] = 0.f;
  }

  const float* cw = P.cw[br];
  const float w00 = cw[e0*4+0], w01 = cw[e0*4+1], w02 = cw[e0*4+2], w03 = cw[e0*4+3];
  const float w10 = cw[(e0+1)*4+0], w11 = cw[(e0+1)*4+1], w12 = cw[(e0+1)*4+2], w13 = cw[(e0+1)*4+3];
  const float cb0 = P.cb[br][e0], cb1 = P.cb[br][e0+1];
  const float* xab = xa + (size_t)b * LL * 512;
  float* xob = xac + ((size_t)(br*2 + b) * LL) * 512;

  float h0x=0,h0y=0,h1x=0,h1y=0,h2x=0,h2y=0,h3x=0,h3y=0;
  #pragma unroll
  for (int i = -3; i < 8; ++i) {
    int l = l0 + i;
    float cx = 0.f, cy = 0.f;
    if (l >= 0 && l < LL) {
      int pos = sigma_map(br, l);
      float2 v = *(const float2*)(xab + (size_t)pos * 512 + e0);
      cx = v.x; cy = v.y;
    }
    h0x=h1x; h0y=h1y; h1x=h2x; h1y=h2y; h2x=h3x; h2y=h3y; h3x=cx; h3y=cy;
    if (i >= 0 && l < LL) {
      float o0 = fmaf(w00,h0x, fmaf(w01,h1x, fmaf(w02,h2x, fmaf(w03,h3x, cb0))));
      float o1 = fmaf(w10,h0y, fmaf(w11,h1y, fmaf(w12,h2y, fmaf(w13,h3y, cb1))));
      *(float2*)(xob + (size_t)l * 512 + e0) = make_float2(silu_f(o0), silu_f(o1));
    }
  }
}

// ---------------------------------------------------------------------------
// k2b: dBC = xc @ xpw^T ; store B,C (bcg) and the 16 R-projections (dbc16).
// delta is NOT materialized (recomputed in k3a/k3b) -> write traffic
// 17.4 MB -> 1.5 MB. 8-row tiles, full-K, grid (129,2,4)=1032 (4/CU).
// thread -> (row = t&7, r = t>>3); waves 0-1 also handle r+32 (uniform).
// ---------------------------------------------------------------------------
__global__ __launch_bounds__(256, 4) void k2b_proj(
    Params P, const float* __restrict__ xac,
    float* __restrict__ dbc16, float* __restrict__ bcg) {
  __shared__ float xcS[8][516];
  __shared__ float dBCs[8][52];
  const int t = threadIdx.x;
  const int l0 = blockIdx.x * 8;
  const int b  = blockIdx.y;
  const int br = blockIdx.z;
  const size_t obase = (size_t)(br*2 + b) * LL;

  // stage 8 rows of xc (1024 float4)
  #pragma unroll
  for (int p = 0; p < 4; ++p) {
    int idx = t + p*256;             // 0..1023
    int row = idx >> 7, c4 = idx & 127;
    int l = l0 + row;
    float4 v = make_float4(0.f,0.f,0.f,0.f);
    if (l < LL) v = *(const float4*)(xac + (obase + l)*512 + c4*4);
    *(float4*)&xcS[row][c4*4] = v;
  }
  __syncthreads();

  const int rowi = t & 7;
  const int rg = t >> 3;           // 0..31
  const float* xpw = P.xpw[br];
  const float4* xr4 = (const float4*)&xcS[rowi][0];
  const float4* wa = (const float4*)(xpw + (size_t)rg * 512);
  float acc0 = 0.f;
  if (rg < 16) {                   // waves 0-1: two dots (r = rg, rg+32)
    const float4* wb = (const float4*)(xpw + (size_t)(rg + 32) * 512);
    float acc1 = 0.f;
    #pragma unroll 8
    for (int e4 = 0; e4 < 128; ++e4) {
      float4 xv = xr4[e4];
      float4 a = wa[e4], bb = wb[e4];
      acc0 = fmaf(xv.x,a.x, fmaf(xv.y,a.y, fmaf(xv.z,a.z, fmaf(xv.w,a.w, acc0))));
      acc1 = fmaf(xv.x,bb.x,fmaf(xv.y,bb.y,fmaf(xv.z,bb.z,fmaf(xv.w,bb.w,acc1))));
    }
    dBCs[rowi][rg]      = acc0;
    dBCs[rowi][rg + 32] = acc1;
  } else {                         // waves 2-3: one dot (r = rg)
    #pragma unroll 8
    for (int e4 = 0; e4 < 128; ++e4) {
      float4 xv = xr4[e4];
      float4 a = wa[e4];
      acc0 = fmaf(xv.x,a.x, fmaf(xv.y,a.y, fmaf(xv.z,a.z, fmaf(xv.w,a.w, acc0))));
    }
    dBCs[rowi][rg] = acc0;
  }
  __syncthreads();

  // write dbc16 (8 rows x 16 r) and bcg (8 rows x 32)
  if (t < 128) {
    int row = t >> 4, r = t & 15;
    int l = l0 + row;
    if (l < LL) dbc16[(obase + l)*16 + r] = dBCs[row][r];
  }
  {
    int row = t >> 5, c = t & 31;
    int l = l0 + row;
    if (l < LL) bcg[(obase + l)*32 + c] = dBCs[row][16 + c];
  }
}

// ---------------------------------------------------------------------------
// k3a: per-chunk scan summaries.  delta recomputed in-LDS from dbc16 + dtw.
// ---------------------------------------------------------------------------
__global__ __launch_bounds__(256, 4) void k3a_chunk(
    Params P, const float* __restrict__ xac, const float* __restrict__ dbc16,
    const float* __restrict__ bcg, float* __restrict__ Pc, float* __restrict__ Qc) {
  __shared__ float dT[16][36], xT[16][36], bT[16][36];
  __shared__ float rT[32][20];
  __shared__ float dtwS[16][17];
  __shared__ float dtbS[16];
  const int t = threadIdx.x;
  const int eL = t >> 4, n = t & 15;
  const int e0 = blockIdx.x * 16;
  const int b = blockIdx.y;
  const int br = blockIdx.z / NC, c = blockIdx.z % NC;
  const size_t sbase = (size_t)(br*2 + b) * LL;
  const float* rb = dbc16 + sbase * 16;
  const float* xc = xac + sbase * 512;
  const float* bc = bcg + sbase * 32;
  const float A_en = -__expf(P.Al[br][(e0 + eL)*16 + n]);
  // stage dtw slice (e0..e0+15) once
  {
    int ee = t >> 4, r = t & 15;
    dtwS[ee][r] = P.dtw[br][(e0 + ee)*16 + r];
    if (t < 16) dtbS[t] = P.dtb[br][e0 + t];
  }
  const int l0 = c * LC;
  const int lend = (c == NC-1) ? LL : (l0 + LC);
  float h = 0.f, dsum = 0.f;
  __syncthreads();

  for (int c0 = l0; c0 < lend; c0 += 32) {
    {
      const int idx = t & 127;
      const int s = idx >> 2, q = idx & 3;
      const int l = c0 + s;
      if (t < 128) {
        float4 v = make_float4(0.f,0.f,0.f,0.f);
        if (l < lend) v = *(const float4*)(rb + (size_t)l*16 + q*4);
        *(float4*)&rT[s][q*4] = v;
        float4 u = make_float4(0.f,0.f,0.f,0.f);
        if (l < lend) u = *(const float4*)(bc + (size_t)l*32 + q*4);
        bT[q*4+0][s]=u.x; bT[q*4+1][s]=u.y; bT[q*4+2][s]=u.z; bT[q*4+3][s]=u.w;
      } else {
        float4 v = make_float4(0.f,0.f,0.f,0.f);
        if (l < lend) v = *(const float4*)(xc + (size_t)l*512 + e0 + q*4);
        xT[q*4+0][s]=v.x; xT[q*4+1][s]=v.y; xT[q*4+2][s]=v.z; xT[q*4+3][s]=v.w;
      }
    }
    __syncthreads();
    // recompute delta for this tile: thread -> (ee = t&15, s, s+16)
    {
      int ee = t & 15, s0 = t >> 4;
      #pragma unroll
      for (int ss = s0; ss < 32; ss += 16) {
        float dv = 0.f;
        if (c0 + ss < lend) {
          float a = dtbS[ee];
          #pragma unroll
          for (int r = 0; r < 16; ++r) a = fmaf(rT[ss][r], dtwS[ee][r], a);
          dv = softplus_f(a);
        }
        dT[ee][ss] = dv;
      }
    }
    __syncthreads();
    #pragma unroll
    for (int s4 = 0; s4 < 32; s4 += 4) {
      float4 dv = *(const float4*)&dT[eL][s4];
      float4 xv = *(const float4*)&xT[eL][s4];
      float4 bv = *(const float4*)&bT[n][s4];
      float g0 = __expf(dv.x*A_en), g1 = __expf(dv.y*A_en);
      float g2 = __expf(dv.z*A_en), g3 = __expf(dv.w*A_en);
      dsum += (dv.x+dv.y)+(dv.z+dv.w);
      h = fmaf(g0, h, dv.x*xv.x*bv.x);
      h = fmaf(g1, h, dv.y*xv.y*bv.y);
      h = fmaf(g2, h, dv.z*xv.z*bv.z);
      h = fmaf(g3, h, dv.w*xv.w*bv.w);
    }
    __syncthreads();
  }
  size_t oi = ((((size_t)(br*2 + b)*NC + c)*32 + blockIdx.x)*256 + t);
  Pc[oi] = __expf(dsum * A_en);
  Qc[oi] = h;
}

// ---------------------------------------------------------------------------
// k3b: chunk-parallel output scan; delta recomputed in-LDS; gated result
// atomically accumulated (x0.25) into acc.
// ---------------------------------------------------------------------------
__global__ __launch_bounds__(256, 4) void k3b_scan(
    Params P, const float* __restrict__ xac, const float* __restrict__ dbc16,
    const float* __restrict__ bcg, const float* __restrict__ sz,
    const float* __restrict__ Pc, const float* __restrict__ Qc,
    float* __restrict__ acc_out) {
  __shared__ float dT[16][36], xT[16][36], bT[16][36], cT[16][36];
  __shared__ float yb[16][36];
  __shared__ float rT[32][20];
  __shared__ float dtwS[16][17];
  __shared__ float dtbS[16];
  const int t = threadIdx.x;
  const int eL = t >> 4, n = t & 15;
  const int e0 = blockIdx.x * 16;
  const int b = blockIdx.y;
  const int br = blockIdx.z / NC, c = blockIdx.z % NC;
  const size_t sbase = (size_t)(br*2 + b) * LL;
  const float* rb = dbc16 + sbase * 16;
  const float* xc = xac + sbase * 512;
  const float* bc = bcg + sbase * 32;
  const float A_en = -__expf(P.Al[br][(e0 + eL)*16 + n]);
  const float Dval = P.Dp[br][e0 + (t & 15)];
  const float* szb = sz + (size_t)b * LL * 512;
  float* ab = acc_out + (size_t)b * LL * 512;
  {
    int ee = t >> 4, r = t & 15;
    dtwS[ee][r] = P.dtw[br][(e0 + ee)*16 + r];
    if (t < 16) dtbS[t] = P.dtb[br][e0 + t];
  }

  // h_in: h[c] = P[c-1]*h[c-1] + Q[c-1], h[0]=0
  float h = 0.f;
  for (int cc = 0; cc < c; ++cc) {
    size_t ii = ((((size_t)(br*2 + b)*NC + cc)*32 + blockIdx.x)*256 + t);
    h = fmaf(Pc[ii], h, Qc[ii]);
  }
  __syncthreads();

  const int l0c = c * LC;
  const int lend = (c == NC-1) ? LL : (l0c + LC);
  for (int c0 = l0c; c0 < lend; c0 += 32) {
    {
      const int idx = t & 127;
      const int s = idx >> 2, q = idx & 3;
      const int l = c0 + s;
      if (t < 128) {
        float4 v = make_float4(0.f,0.f,0.f,0.f);
        if (l < lend) v = *(const float4*)(rb + (size_t)l*16 + q*4);
        *(float4*)&rT[s][q*4] = v;
      } else {
        float4 v = make_float4(0.f,0.f,0.f,0.f);
        if (l < lend) v = *(const float4*)(xc + (size_t)l*512 + e0 + q*4);
        xT[q*4+0][s]=v.x; xT[q*4+1][s]=v.y; xT[q*4+2][s]=v.z; xT[q*4+3][s]=v.w;
      }
    }
    {
      const int s = t >> 3, q = t & 7;
      const int l = c0 + s;
      float4 u = make_float4(0.f,0.f,0.f,0.f);
      if (l < lend) u = *(const float4*)(bc + (size_t)l*32 + q*4);
      if (q < 4) {
        bT[q*4+0][s]=u.x; bT[q*4+1][s]=u.y; bT[q*4+2][s]=u.z; bT[q*4+3][s]=u.w;
      } else {
        int q4 = (q-4)*4;
        cT[q4+0][s]=u.x; cT[q4+1][s]=u.y; cT[q4+2][s]=u.z; cT[q4+3][s]=u.w;
      }
    }
    __syncthreads();
    // recompute delta for this tile
    {
      int ee = t & 15, s0 = t >> 4;
      #pragma unroll
      for (int ss = s0; ss < 32; ss += 16) {
        float dv = 0.f;
        if (c0 + ss < lend) {
          float a = dtbS[ee];
          #pragma unroll
          for (int r = 0; r < 16; ++r) a = fmaf(rT[ss][r], dtwS[ee][r], a);
          dv = softplus_f(a);
        }
        dT[ee][ss] = dv;
      }
    }
    __syncthreads();

    #pragma unroll
    for (int s4 = 0; s4 < 32; s4 += 4) {
      float4 dv = *(const float4*)&dT[eL][s4];
      float4 xv = *(const float4*)&xT[eL][s4];
      float4 bv = *(const float4*)&bT[n][s4];
      float4 cv = *(const float4*)&cT[n][s4];
      float r0, r1, r2, r3;
      h = fmaf(__expf(dv.x*A_en), h, dv.x*xv.x*bv.x); r0 = red16(h*cv.x);
      h = fmaf(__expf(dv.y*A_en), h, dv.y*xv.y*bv.y); r1 = red16(h*cv.y);
      h = fmaf(__expf(dv.z*A_en), h, dv.z*xv.z*bv.z); r2 = red16(h*cv.z);
      h = fmaf(__expf(dv.w*A_en), h, dv.w*xv.w*bv.w); r3 = red16(h*cv.w);
      if (n == 15) *(float4*)&yb[eL][s4] = make_float4(r0, r1, r2, r3);
    }
    __syncthreads();

    #pragma unroll
    for (int p = 0; p < 2; ++p) {
      int idx = t + p*256;
      int s = idx >> 4, ee = idx & 15;
      int l = c0 + s;
      if (l < lend) {
        float yv = fmaf(Dval, xT[ee][s], yb[ee][s]);
        int pos = sigma_map(br, l);
        float szv = szb[(size_t)pos * 512 + e0 + ee];
        atomicAdd(ab + (size_t)pos * 512 + e0 + ee, 0.25f * yv * szv);
      }
    }
    __syncthreads();
  }
}

// ---------------------------------------------------------------------------
// k4: out = acc @ out_w^T.  M=2052 N=256 K=512.  BM=32 BN=32 grid (65,8).
// ---------------------------------------------------------------------------
__global__ __launch_bounds__(256, 2) void k4_gemm_out(
    const float* __restrict__ acc_in, const float* __restrict__ w,
    float* __restrict__ out) {
  __shared__ float As[32][38];
  __shared__ float Bs[32][38];
  const int t = threadIdx.x;
  const int tx = t & 15, ty = t >> 4;
  const int m0 = blockIdx.x * 32, n0 = blockIdx.y * 32;
  float acc[2][2] = {};
  for (int k0 = 0; k0 < 512; k0 += 32) {
    #pragma unroll
    for (int p = 0; p < 4; ++p) {
      int idx = t + p*256;
      int row = idx >> 5, kk = idx & 31;
      int gm = m0 + row; gm = gm < MM ? gm : MM - 1;
      As[kk][row] = acc_in[(size_t)gm*512 + k0 + kk];
    }
    #pragma unroll
    for (int p = 0; p < 4; ++p) {
      int idx = t + p*256;
      int row = idx >> 5, kk = idx & 31;
      Bs[kk][row] = w[(size_t)(n0 + row)*512 + k0 + kk];
    }
    __syncthreads();
    #pragma unroll
    for (int k = 0; k < 32; ++k) {
      float2 av = *(const float2*)&As[k][ty*2];
      float2 bv = *(const float2*)&Bs[k][tx*2];
      acc[0][0]=fmaf(av.x,bv.x,acc[0][0]); acc[0][1]=fmaf(av.x,bv.y,acc[0][1]);
      acc[1][0]=fmaf(av.y,bv.x,acc[1][0]); acc[1][1]=fmaf(av.y,bv.y,acc[1][1]);
    }
    __syncthreads();
  }
  #pragma unroll
  for (int i = 0; i < 2; ++i) {
    int gm = m0 + ty*2 + i;
    if (gm < MM) {
      #pragma unroll
      for (int j = 0; j < 2; ++j)
        out[(size_t)gm*256 + n0 + tx*2 + j] = acc[i][j];
    }
  }
}

// ---------------------------------------------------------------------------
extern "C" void kernel_launch(void* const* d_in, const int* in_sizes, int n_in,
                              void* d_out, int out_size, void* d_ws, size_t ws_size,
                              hipStream_t stream) {
  const float* x    = (const float*)d_in[0];
  const float* in_w = (const float*)d_in[1];
  const float* out_w= (const float*)d_in[2];
  Params prm;
  for (int s = 0; s < 4; ++s) {
    prm.cw[s]  = (const float*)d_in[3 + s*7 + 0];
    prm.cb[s]  = (const float*)d_in[3 + s*7 + 1];
    prm.xpw[s] = (const float*)d_in[3 + s*7 + 2];
    prm.dtw[s] = (const float*)d_in[3 + s*7 + 3];
    prm.dtb[s] = (const float*)d_in[3 + s*7 + 4];
    prm.Al[s]  = (const float*)d_in[3 + s*7 + 5];
    prm.Dp[s]  = (const float*)d_in[3 + s*7 + 6];
  }
  float* ws = (float*)d_ws;
  const size_t SZ1 = (size_t)MM * 512;           // 1,050,624 floats
  float* xa    = ws;                              // [MM][512]
  float* szp   = ws + SZ1;                        // [MM][512]
  float* xac   = ws + 2*SZ1;                      // [4][MM][512] branch-ordered
  float* bc    = ws + 6*SZ1;                      // [4][MM][32]
  float* acc   = bc + (size_t)4*MM*32;            // [MM][512]
  float* Pc    = acc + SZ1;                       // [8][NC][32][256]
  float* Qc    = Pc + (size_t)8*NC*32*256;        // same size
  float* dbc16 = Qc + (size_t)8*NC*32*256;        // [8][LL][16]

  k1_gemm_in<<<dim3(33, 16), 256, 0, stream>>>(x, in_w, xa, szp);
  k2a_conv  <<<dim3(129, 2, 4), 256, 0, stream>>>(prm, xa, xac, acc);
  k2b_proj  <<<dim3(129, 2, 4), 256, 0, stream>>>(prm, xac, dbc16, bc);
  k3a_chunk <<<dim3(32, 2, 4*NC), 256, 0, stream>>>(prm, xac, dbc16, bc, Pc, Qc);
  k3b_scan  <<<dim3(32, 2, 4*NC), 256, 0, stream>>>(prm, xac, dbc16, bc, szp, Pc, Qc, acc);
  k4_gemm_out<<<dim3(65, 8), 256, 0, stream>>>(acc, out_w, (float*)d_out);
}